// Round 1
// baseline (2971.220 us; speedup 1.0000x reference)
//
#include <hip/hip_runtime.h>
#include <math.h>

#define B 8192
#define D 128
#define C 1000
#define EPS 1e-6f
#define LAMBD 0.1f

// ws layout (float slots):
// [0] ce_acc   [1] feat_acc
// [64          .. 64+B)   e[i]  = sq_i + 2*EPS*s_i
// [64+B        .. 64+2B)  f[j]  = sq_j - 2*EPS*s_j
// [64+2B       .. 64+3B)  dpos[i]
// [64+3B       .. 64+4B)  dtot[i]
// [64+4B       .. +C ints) fo[c] = first occurrence index of class c

__global__ void k_init(float* ws) {
    int t = blockIdx.x * 256 + threadIdx.x;
    if (t < 2) ws[t] = 0.f;
    if (t < B) ws[64 + 3 * B + t] = 0.f;
    int* fo = (int*)(ws + 64 + 4 * B);
    if (t < C) fo[t] = 0x7fffffff;
}

__global__ void k_rowstats(const float* __restrict__ x, const int* __restrict__ y,
                           float* ws) {
    int row = blockIdx.x * 4 + (threadIdx.x >> 6);
    int lane = threadIdx.x & 63;
    float v0 = x[row * D + lane];
    float v1 = x[row * D + 64 + lane];
    float sq = v0 * v0 + v1 * v1;
    float s = v0 + v1;
    for (int o = 32; o; o >>= 1) {
        sq += __shfl_xor(sq, o);
        s += __shfl_xor(s, o);
    }
    if (lane == 0) {
        ws[64 + row] = sq + 2.f * EPS * s;
        ws[64 + B + row] = sq - 2.f * EPS * s;
        atomicMin((int*)(ws + 64 + 4 * B) + y[row], row);
    }
}

__global__ void k_ce(const float* __restrict__ data, const int* __restrict__ y,
                     float* ws) {
    int row = blockIdx.x;
    int t = threadIdx.x;
    const float* dr = data + (size_t)row * C;
    float v[4];
    float m = -1e30f;
#pragma unroll
    for (int k = 0; k < 4; k++) {
        int j = t + k * 256;
        v[k] = (j < C) ? dr[j] : -1e30f;
        m = fmaxf(m, v[k]);
    }
    for (int o = 32; o; o >>= 1) m = fmaxf(m, __shfl_xor(m, o));
    __shared__ float sm[4];
    __shared__ float ss[4];
    int w = t >> 6, lane = t & 63;
    if (lane == 0) sm[w] = m;
    __syncthreads();
    m = fmaxf(fmaxf(sm[0], sm[1]), fmaxf(sm[2], sm[3]));
    float sum = 0.f;
#pragma unroll
    for (int k = 0; k < 4; k++) {
        int j = t + k * 256;
        if (j < C) sum += __expf(v[k] - m);
    }
    for (int o = 32; o; o >>= 1) sum += __shfl_xor(sum, o);
    if (lane == 0) ss[w] = sum;
    __syncthreads();
    if (t == 0) {
        float tot = ss[0] + ss[1] + ss[2] + ss[3];
        float lse = m + __logf(tot);
        float contrib = lse - dr[y[row]];
        atomicAdd(ws + 0, contrib);
    }
}

__global__ void k_dpos(const float* __restrict__ x, const int* __restrict__ y,
                       float* ws) {
    int row = blockIdx.x * 4 + (threadIdx.x >> 6);
    int lane = threadIdx.x & 63;
    const int* fo = (const int*)(ws + 64 + 4 * B);
    int fp = fo[y[row]];
    float d0 = x[row * D + lane] - x[fp * D + lane] + EPS;
    float d1 = x[row * D + 64 + lane] - x[fp * D + 64 + lane] + EPS;
    float sq = d0 * d0 + d1 * d1;
    for (int o = 32; o; o >>= 1) sq += __shfl_xor(sq, o);
    if (lane == 0) ws[64 + 2 * B + row] = sqrtf(sq);
}

// Main kernel: dtot[i] = sum_j sqrt(max(e_i + f_j - 2*dot(x_i,x_j) + D*EPS^2, 0))
// Grid (64, 8): blockIdx.x = i-band of 128 rows, blockIdx.y = 1024-wide j slice.
// 256 threads as 16x16; each thread computes an 8x8 micro-tile.
__global__ void __launch_bounds__(256, 2)
k_dtot(const float* __restrict__ x, float* ws) {
    __shared__ float4 la[128 * 8];  // [row][8 quads], quad-index XOR-swizzled
    __shared__ float4 lb[128 * 8];
    const float4* x4 = (const float4*)x;
    int t = threadIdx.x;
    int tx = t & 15, ty = t >> 4;
    int i0 = blockIdx.x * 128;
    int jbase = blockIdx.y * 1024;
    const float* e = ws + 64;
    const float* f = ws + 64 + B;
    float* dtot = ws + 64 + 3 * B;

    float er[8], rsum[8];
#pragma unroll
    for (int r = 0; r < 8; r++) {
        er[r] = e[i0 + ty * 8 + r];
        rsum[r] = 0.f;
    }
    const float deps2 = (float)D * EPS * EPS;

    for (int jt = 0; jt < 8; ++jt) {
        int j0 = jbase + jt * 128;
        float acc[8][8];
#pragma unroll
        for (int r = 0; r < 8; r++)
#pragma unroll
            for (int c = 0; c < 8; c++) acc[r][c] = 0.f;

        for (int kc = 0; kc < 4; ++kc) {
            __syncthreads();
#pragma unroll
            for (int it = 0; it < 4; ++it) {
                int idx = t + it * 256;  // 0..1023 = 128 rows x 8 quads
                int row = idx >> 3, q = idx & 7;
                int swq = q ^ ((row >> 3) & 7);
                la[row * 8 + swq] = x4[(size_t)(i0 + row) * 32 + kc * 8 + q];
                lb[row * 8 + swq] = x4[(size_t)(jbase + jt * 128 + row) * 32 + kc * 8 + q];
            }
            __syncthreads();
#pragma unroll
            for (int kq = 0; kq < 8; ++kq) {
                float4 a[8];
#pragma unroll
                for (int r = 0; r < 8; r++)
                    a[r] = la[(ty * 8 + r) * 8 + (kq ^ (ty & 7))];
#pragma unroll
                for (int c = 0; c < 8; c++) {
                    float4 b = lb[(tx * 8 + c) * 8 + (kq ^ (tx & 7))];
#pragma unroll
                    for (int r = 0; r < 8; r++)
                        acc[r][c] += a[r].x * b.x + a[r].y * b.y +
                                     a[r].z * b.z + a[r].w * b.w;
                }
            }
        }
        // epilogue: d2 -> dist -> row sums
#pragma unroll
        for (int c = 0; c < 8; c++) {
            float fc = f[j0 + tx * 8 + c];
#pragma unroll
            for (int r = 0; r < 8; r++) {
                float d2 = er[r] + fc - 2.f * acc[r][c] + deps2;
                rsum[r] += sqrtf(fmaxf(d2, 0.f));
            }
        }
    }
    // reduce across the 16 tx lanes sharing each i-row
#pragma unroll
    for (int r = 0; r < 8; r++) {
        float v = rsum[r];
        v += __shfl_xor(v, 1);
        v += __shfl_xor(v, 2);
        v += __shfl_xor(v, 4);
        v += __shfl_xor(v, 8);
        if (tx == 0) atomicAdd(&dtot[i0 + ty * 8 + r], v);
    }
}

__global__ void k_feat(float* ws) {
    int i = blockIdx.x * 256 + threadIdx.x;
    float ratio = 0.f;
    if (i < B) {
        float dp = ws[64 + 2 * B + i];
        float dt = ws[64 + 3 * B + i];
        ratio = dp / (dt - dp);
    }
    for (int o = 32; o; o >>= 1) ratio += __shfl_xor(ratio, o);
    __shared__ float sm[4];
    int w = threadIdx.x >> 6;
    if ((threadIdx.x & 63) == 0) sm[w] = ratio;
    __syncthreads();
    if (threadIdx.x == 0) atomicAdd(ws + 1, sm[0] + sm[1] + sm[2] + sm[3]);
}

__global__ void k_out(const float* __restrict__ ws, float* __restrict__ out) {
    float la = ws[0] / (float)B;
    float lf = ws[1];
    out[0] = la + LAMBD * lf;
    out[1] = la;
    out[2] = lf;
}

extern "C" void kernel_launch(void* const* d_in, const int* in_sizes, int n_in,
                              void* d_out, int out_size, void* d_ws, size_t ws_size,
                              hipStream_t stream) {
    const float* data = (const float*)d_in[0];
    const float* x = (const float*)d_in[1];
    const int* y = (const int*)d_in[2];
    float* out = (float*)d_out;
    float* ws = (float*)d_ws;

    k_init<<<(B + 255) / 256, 256, 0, stream>>>(ws);
    k_rowstats<<<B / 4, 256, 0, stream>>>(x, y, ws);
    k_ce<<<B, 256, 0, stream>>>(data, y, ws);
    k_dpos<<<B / 4, 256, 0, stream>>>(x, y, ws);
    k_dtot<<<dim3(64, 8), 256, 0, stream>>>(x, ws);
    k_feat<<<(B + 255) / 256, 256, 0, stream>>>(ws);
    k_out<<<1, 1, 0, stream>>>(ws, out);
}

// Round 2
// 268.321 us; speedup vs baseline: 11.0734x; 11.0734x over previous
//
#include <hip/hip_runtime.h>
#include <math.h>

#define B 8192
#define D 128
#define C 1000
#define EPS 1e-6f
#define LAMBD 0.1f

typedef __attribute__((ext_vector_type(8))) short short8;
typedef __attribute__((ext_vector_type(4))) float floatx4;

// ws layout (float slots):
// [0] ce_acc   [1] feat_acc
// [64          .. 64+B)   e[i]  = sq_i + 2*EPS*s_i
// [64+B        .. 64+2B)  f[j]  = sq_j - 2*EPS*s_j
// [64+2B       .. 64+3B)  dpos[i]
// [64+3B       .. 64+4B)  dtot[i]
// [64+4B       .. +C ints) fo[c] = first occurrence index of class c

__device__ inline short f2bf(float f) {
    union { float f; unsigned u; } v; v.f = f;
    unsigned u = v.u;
    unsigned r = (u + 0x7fffu + ((u >> 16) & 1u)) >> 16;  // RTNE
    return (short)r;
}

__global__ void k_init(float* ws) {
    int t = blockIdx.x * 256 + threadIdx.x;
    if (t < 2) ws[t] = 0.f;
    if (t < B) ws[64 + 3 * B + t] = 0.f;
    int* fo = (int*)(ws + 64 + 4 * B);
    if (t < C) fo[t] = 0x7fffffff;
}

__global__ void k_rowstats(const float* __restrict__ x, const int* __restrict__ y,
                           float* ws) {
    int row = blockIdx.x * 4 + (threadIdx.x >> 6);
    int lane = threadIdx.x & 63;
    float v0 = x[row * D + lane];
    float v1 = x[row * D + 64 + lane];
    float sq = v0 * v0 + v1 * v1;
    float s = v0 + v1;
    for (int o = 32; o; o >>= 1) {
        sq += __shfl_xor(sq, o);
        s += __shfl_xor(s, o);
    }
    if (lane == 0) {
        ws[64 + row] = sq + 2.f * EPS * s;
        ws[64 + B + row] = sq - 2.f * EPS * s;
        atomicMin((int*)(ws + 64 + 4 * B) + y[row], row);
    }
}

__global__ void k_ce(const float* __restrict__ data, const int* __restrict__ y,
                     float* ws) {
    int row = blockIdx.x;
    int t = threadIdx.x;
    const float* dr = data + (size_t)row * C;
    float v[4];
    float m = -1e30f;
#pragma unroll
    for (int k = 0; k < 4; k++) {
        int j = t + k * 256;
        v[k] = (j < C) ? dr[j] : -1e30f;
        m = fmaxf(m, v[k]);
    }
    for (int o = 32; o; o >>= 1) m = fmaxf(m, __shfl_xor(m, o));
    __shared__ float sm[4];
    __shared__ float ss[4];
    int w = t >> 6, lane = t & 63;
    if (lane == 0) sm[w] = m;
    __syncthreads();
    m = fmaxf(fmaxf(sm[0], sm[1]), fmaxf(sm[2], sm[3]));
    float sum = 0.f;
#pragma unroll
    for (int k = 0; k < 4; k++) {
        int j = t + k * 256;
        if (j < C) sum += __expf(v[k] - m);
    }
    for (int o = 32; o; o >>= 1) sum += __shfl_xor(sum, o);
    if (lane == 0) ss[w] = sum;
    __syncthreads();
    if (t == 0) {
        float tot = ss[0] + ss[1] + ss[2] + ss[3];
        float lse = m + __logf(tot);
        float contrib = lse - dr[y[row]];
        atomicAdd(ws + 0, contrib);
    }
}

__global__ void k_dpos(const float* __restrict__ x, const int* __restrict__ y,
                       float* ws) {
    int row = blockIdx.x * 4 + (threadIdx.x >> 6);
    int lane = threadIdx.x & 63;
    const int* fo = (const int*)(ws + 64 + 4 * B);
    int fp = fo[y[row]];
    float d0 = x[row * D + lane] - x[fp * D + lane] + EPS;
    float d1 = x[row * D + 64 + lane] - x[fp * D + 64 + lane] + EPS;
    float sq = d0 * d0 + d1 * d1;
    for (int o = 32; o; o >>= 1) sq += __shfl_xor(sq, o);
    if (lane == 0) ws[64 + 2 * B + row] = sqrtf(sq);
}

// Gram + dist + row-sum via MFMA. Block = 128x128 output tile, K=128 (one shot).
// 4 waves in 2x2; each wave does 64x64 via 4x4 frags of 16x16x32 bf16 MFMA.
// LDS tiles XOR-swizzled: chunk(16B) index ^= (row&7)  -> conflict-free b128 reads.
__global__ void __launch_bounds__(256)
k_gram_dtot(const float* __restrict__ x, float* ws) {
    __shared__ short lA[128 * 128];
    __shared__ short lB[128 * 128];
    __shared__ float sdtot[128];
    const float4* x4 = (const float4*)x;
    int t = threadIdx.x;
    int i0 = blockIdx.y * 128, j0 = blockIdx.x * 128;

    // stage + f32->bf16 convert: 128 rows x 16 chunks (8 bf16 each) per tile
#pragma unroll
    for (int it = 0; it < 8; ++it) {
        int idx = it * 256 + t;
        int row = idx >> 4, ch = idx & 15;
        int sw = (ch ^ (row & 7)) * 8;
        float4 a0 = x4[(size_t)(i0 + row) * 32 + ch * 2];
        float4 a1 = x4[(size_t)(i0 + row) * 32 + ch * 2 + 1];
        float4 b0 = x4[(size_t)(j0 + row) * 32 + ch * 2];
        float4 b1 = x4[(size_t)(j0 + row) * 32 + ch * 2 + 1];
        short8 sa = { f2bf(a0.x), f2bf(a0.y), f2bf(a0.z), f2bf(a0.w),
                      f2bf(a1.x), f2bf(a1.y), f2bf(a1.z), f2bf(a1.w) };
        short8 sb = { f2bf(b0.x), f2bf(b0.y), f2bf(b0.z), f2bf(b0.w),
                      f2bf(b1.x), f2bf(b1.y), f2bf(b1.z), f2bf(b1.w) };
        *(short8*)&lA[row * 128 + sw] = sa;
        *(short8*)&lB[row * 128 + sw] = sb;
    }
    if (t < 128) sdtot[t] = 0.f;
    __syncthreads();

    int lane = t & 63, wid = t >> 6;
    int wm = wid >> 1, wn = wid & 1;
    int lo = lane & 15, hi = lane >> 4;

    floatx4 acc[4][4];
#pragma unroll
    for (int mr = 0; mr < 4; ++mr)
#pragma unroll
        for (int nr = 0; nr < 4; ++nr) acc[mr][nr] = (floatx4){0.f, 0.f, 0.f, 0.f};

#pragma unroll
    for (int kt = 0; kt < 4; ++kt) {
        short8 af[4], bg[4];
        int ch = kt * 4 + hi;
#pragma unroll
        for (int mr = 0; mr < 4; ++mr) {
            int r = wm * 64 + mr * 16 + lo;
            af[mr] = *(const short8*)&lA[r * 128 + (ch ^ (r & 7)) * 8];
        }
#pragma unroll
        for (int nr = 0; nr < 4; ++nr) {
            int r = wn * 64 + nr * 16 + lo;
            bg[nr] = *(const short8*)&lB[r * 128 + (ch ^ (r & 7)) * 8];
        }
#pragma unroll
        for (int mr = 0; mr < 4; ++mr)
#pragma unroll
            for (int nr = 0; nr < 4; ++nr)
                acc[mr][nr] = __builtin_amdgcn_mfma_f32_16x16x32_bf16(
                    af[mr], bg[nr], acc[mr][nr], 0, 0, 0);
    }

    // epilogue: d2 = e_i + f_j - 2g + D*EPS^2 ; dist = sqrt(max(.,0)); row sums
    const float* e = ws + 64;
    const float* f = ws + 64 + B;
    float* dtot = ws + 64 + 3 * B;
    const float deps2 = (float)D * EPS * EPS;

    float er[4][4];
#pragma unroll
    for (int mr = 0; mr < 4; ++mr)
#pragma unroll
        for (int rg = 0; rg < 4; ++rg)
            er[mr][rg] = e[i0 + wm * 64 + mr * 16 + hi * 4 + rg];
    float fc[4];
#pragma unroll
    for (int nr = 0; nr < 4; ++nr) fc[nr] = f[j0 + wn * 64 + nr * 16 + lo];

    float rs[4][4];
#pragma unroll
    for (int mr = 0; mr < 4; ++mr)
#pragma unroll
        for (int rg = 0; rg < 4; ++rg) rs[mr][rg] = 0.f;

#pragma unroll
    for (int mr = 0; mr < 4; ++mr)
#pragma unroll
        for (int nr = 0; nr < 4; ++nr)
#pragma unroll
            for (int rg = 0; rg < 4; ++rg) {
                float d2 = er[mr][rg] + fc[nr] - 2.f * acc[mr][nr][rg] + deps2;
                rs[mr][rg] += sqrtf(fmaxf(d2, 0.f));
            }

#pragma unroll
    for (int mr = 0; mr < 4; ++mr)
#pragma unroll
        for (int rg = 0; rg < 4; ++rg) {
            float v = rs[mr][rg];
            v += __shfl_xor(v, 1);
            v += __shfl_xor(v, 2);
            v += __shfl_xor(v, 4);
            v += __shfl_xor(v, 8);
            if (lo == 0) atomicAdd(&sdtot[wm * 64 + mr * 16 + hi * 4 + rg], v);
        }
    __syncthreads();
    if (t < 128) atomicAdd(&dtot[i0 + t], sdtot[t]);
}

__global__ void k_feat(float* ws) {
    int i = blockIdx.x * 256 + threadIdx.x;
    float ratio = 0.f;
    if (i < B) {
        float dp = ws[64 + 2 * B + i];
        float dt = ws[64 + 3 * B + i];
        ratio = dp / (dt - dp);
    }
    for (int o = 32; o; o >>= 1) ratio += __shfl_xor(ratio, o);
    __shared__ float sm[4];
    int w = threadIdx.x >> 6;
    if ((threadIdx.x & 63) == 0) sm[w] = ratio;
    __syncthreads();
    if (threadIdx.x == 0) atomicAdd(ws + 1, sm[0] + sm[1] + sm[2] + sm[3]);
}

__global__ void k_out(const float* __restrict__ ws, float* __restrict__ out) {
    float la = ws[0] / (float)B;
    float lf = ws[1];
    out[0] = la + LAMBD * lf;
    out[1] = la;
    out[2] = lf;
}

extern "C" void kernel_launch(void* const* d_in, const int* in_sizes, int n_in,
                              void* d_out, int out_size, void* d_ws, size_t ws_size,
                              hipStream_t stream) {
    const float* data = (const float*)d_in[0];
    const float* x = (const float*)d_in[1];
    const int* y = (const int*)d_in[2];
    float* out = (float*)d_out;
    float* ws = (float*)d_ws;

    k_init<<<(B + 255) / 256, 256, 0, stream>>>(ws);
    k_rowstats<<<B / 4, 256, 0, stream>>>(x, y, ws);
    k_ce<<<B, 256, 0, stream>>>(data, y, ws);
    k_dpos<<<B / 4, 256, 0, stream>>>(x, y, ws);
    k_gram_dtot<<<dim3(64, 64), 256, 0, stream>>>(x, ws);
    k_feat<<<(B + 255) / 256, 256, 0, stream>>>(ws);
    k_out<<<1, 1, 0, stream>>>(ws, out);
}

// Round 7
// 176.585 us; speedup vs baseline: 16.8260x; 1.5195x over previous
//
#include <hip/hip_runtime.h>
#include <math.h>

#define B 8192
#define D 128
#define C 1000
#define EPS 1e-6f
#define LAMBD 0.1f

typedef __attribute__((ext_vector_type(8))) short short8;
typedef __attribute__((ext_vector_type(4))) float floatx4;

// ws layout (float slots):
// [0] ce_acc   [1] feat_acc
// [64          .. 64+B)   e[i]  = sq_i + 2*EPS*s_i
// [64+B        .. 64+2B)  f[j]  = sq_j - 2*EPS*s_j
// [64+2B       .. 64+3B)  dpos[i]
// [64+3B       .. 64+4B)  dtot[i]
// [64+4B       .. +C ints) fo[c] = first occurrence index of class c

__device__ inline short f2bf(float f) {
    union { float f; unsigned u; } v; v.f = f;
    unsigned u = v.u;
    unsigned r = (u + 0x7fffu + ((u >> 16) & 1u)) >> 16;  // RTNE
    return (short)r;
}

__global__ void k_init(float* ws) {
    int t = blockIdx.x * 256 + threadIdx.x;
    if (t < 2) ws[t] = 0.f;
    if (t < B) ws[64 + 3 * B + t] = 0.f;
    int* fo = (int*)(ws + 64 + 4 * B);
    if (t < C) fo[t] = 0x7fffffff;
}

__global__ void k_rowstats(const float* __restrict__ x, const int* __restrict__ y,
                           float* ws) {
    int row = blockIdx.x * 4 + (threadIdx.x >> 6);
    int lane = threadIdx.x & 63;
    float v0 = x[row * D + lane];
    float v1 = x[row * D + 64 + lane];
    float sq = v0 * v0 + v1 * v1;
    float s = v0 + v1;
    for (int o = 32; o; o >>= 1) {
        sq += __shfl_xor(sq, o);
        s += __shfl_xor(s, o);
    }
    if (lane == 0) {
        ws[64 + row] = sq + 2.f * EPS * s;
        ws[64 + B + row] = sq - 2.f * EPS * s;
        atomicMin((int*)(ws + 64 + 4 * B) + y[row], row);
    }
}

// wave-per-row CE: 4 rows / 256-thread block, no barriers in the hot path.
__global__ void __launch_bounds__(256)
k_ce(const float* __restrict__ data, const int* __restrict__ y, float* ws) {
    int row = blockIdx.x * 4 + (threadIdx.x >> 6);
    int lane = threadIdx.x & 63;
    const float* dr = data + (size_t)row * C;
    const float4* dr4 = (const float4*)dr;  // row*4000B is 16B-aligned

    float4 v[4];
    float m = -1e30f;
#pragma unroll
    for (int k = 0; k < 4; k++) {
        int idx = k * 64 + lane;
        if (idx < C / 4) {
            v[k] = dr4[idx];
            m = fmaxf(fmaxf(fmaxf(m, v[k].x), fmaxf(v[k].y, v[k].z)), v[k].w);
        }
    }
    for (int o = 32; o; o >>= 1) m = fmaxf(m, __shfl_xor(m, o));

    float sum = 0.f;
#pragma unroll
    for (int k = 0; k < 4; k++) {
        int idx = k * 64 + lane;
        if (idx < C / 4) {
            sum += __expf(v[k].x - m) + __expf(v[k].y - m) +
                   __expf(v[k].z - m) + __expf(v[k].w - m);
        }
    }
    for (int o = 32; o; o >>= 1) sum += __shfl_xor(sum, o);

    __shared__ float sp[4];
    if (lane == 0) {
        float lse = m + __logf(sum);
        sp[threadIdx.x >> 6] = lse - dr[y[row]];
    }
    __syncthreads();
    if (threadIdx.x == 0)
        atomicAdd(ws + 0, sp[0] + sp[1] + sp[2] + sp[3]);
}

__global__ void k_dpos(const float* __restrict__ x, const int* __restrict__ y,
                       float* ws) {
    int row = blockIdx.x * 4 + (threadIdx.x >> 6);
    int lane = threadIdx.x & 63;
    const int* fo = (const int*)(ws + 64 + 4 * B);
    int fp = fo[y[row]];
    float d0 = x[row * D + lane] - x[fp * D + lane] + EPS;
    float d1 = x[row * D + 64 + lane] - x[fp * D + 64 + lane] + EPS;
    float sq = d0 * d0 + d1 * d1;
    for (int o = 32; o; o >>= 1) sq += __shfl_xor(sq, o);
    if (lane == 0) ws[64 + 2 * B + row] = sqrtf(sq);
}

// Gram + dist + row/col sums via MFMA, upper-triangle blocks only (j >= i).
// dist(j,i) ~= dist(i,j) up to the +-2*EPS*(s_i-s_j) term (~1e-5 abs, noise).
// Block = 128x128 tile, K=128 one shot; 4 waves 2x2; 4x4 frags of 16x16x32 bf16.
__global__ void __launch_bounds__(256)
k_gram_dtot(const float* __restrict__ x, float* ws) {
    int bj = blockIdx.x, bi = blockIdx.y;
    if (bj < bi) return;  // lower triangle handled by symmetry
    bool offdiag = (bj != bi);

    __shared__ short lA[128 * 128];
    __shared__ short lB[128 * 128];
    __shared__ float sdrow[128];
    __shared__ float sdcol[128];
    const float4* x4 = (const float4*)x;
    int t = threadIdx.x;
    int i0 = bi * 128, j0 = bj * 128;

    // stage + f32->bf16 convert: 128 rows x 16 chunks (8 bf16 each) per tile
#pragma unroll
    for (int it = 0; it < 8; ++it) {
        int idx = it * 256 + t;
        int row = idx >> 4, ch = idx & 15;
        int sw = (ch ^ (row & 7)) * 8;
        float4 a0 = x4[(size_t)(i0 + row) * 32 + ch * 2];
        float4 a1 = x4[(size_t)(i0 + row) * 32 + ch * 2 + 1];
        float4 b0 = x4[(size_t)(j0 + row) * 32 + ch * 2];
        float4 b1 = x4[(size_t)(j0 + row) * 32 + ch * 2 + 1];
        short8 sa = { f2bf(a0.x), f2bf(a0.y), f2bf(a0.z), f2bf(a0.w),
                      f2bf(a1.x), f2bf(a1.y), f2bf(a1.z), f2bf(a1.w) };
        short8 sb = { f2bf(b0.x), f2bf(b0.y), f2bf(b0.z), f2bf(b0.w),
                      f2bf(b1.x), f2bf(b1.y), f2bf(b1.z), f2bf(b1.w) };
        *(short8*)&lA[row * 128 + sw] = sa;
        *(short8*)&lB[row * 128 + sw] = sb;
    }
    if (t < 128) { sdrow[t] = 0.f; sdcol[t] = 0.f; }
    __syncthreads();

    int lane = t & 63, wid = t >> 6;
    int wm = wid >> 1, wn = wid & 1;
    int lo = lane & 15, hi = lane >> 4;

    floatx4 acc[4][4];
#pragma unroll
    for (int mr = 0; mr < 4; ++mr)
#pragma unroll
        for (int nr = 0; nr < 4; ++nr) acc[mr][nr] = (floatx4){0.f, 0.f, 0.f, 0.f};

#pragma unroll
    for (int kt = 0; kt < 4; ++kt) {
        short8 af[4], bg[4];
        int ch = kt * 4 + hi;
#pragma unroll
        for (int mr = 0; mr < 4; ++mr) {
            int r = wm * 64 + mr * 16 + lo;
            af[mr] = *(const short8*)&lA[r * 128 + (ch ^ (r & 7)) * 8];
        }
#pragma unroll
        for (int nr = 0; nr < 4; ++nr) {
            int r = wn * 64 + nr * 16 + lo;
            bg[nr] = *(const short8*)&lB[r * 128 + (ch ^ (r & 7)) * 8];
        }
#pragma unroll
        for (int mr = 0; mr < 4; ++mr)
#pragma unroll
            for (int nr = 0; nr < 4; ++nr)
                acc[mr][nr] = __builtin_amdgcn_mfma_f32_16x16x32_bf16(
                    af[mr], bg[nr], acc[mr][nr], 0, 0, 0);
    }

    // epilogue: d2 = e_i + f_j - 2g + D*EPS^2 ; dist = sqrt(max(.,0))
    const float* e = ws + 64;
    const float* f = ws + 64 + B;
    float* dtot = ws + 64 + 3 * B;
    const float deps2 = (float)D * EPS * EPS;

    float er[4][4];
#pragma unroll
    for (int mr = 0; mr < 4; ++mr)
#pragma unroll
        for (int rg = 0; rg < 4; ++rg)
            er[mr][rg] = e[i0 + wm * 64 + mr * 16 + hi * 4 + rg];
    float fc[4];
#pragma unroll
    for (int nr = 0; nr < 4; ++nr) fc[nr] = f[j0 + wn * 64 + nr * 16 + lo];

    float rs[4][4];  // row partial sums (per i-row owned by this lane)
    float cs[4];     // col partial sums (per j-col owned by this lane)
#pragma unroll
    for (int mr = 0; mr < 4; ++mr)
#pragma unroll
        for (int rg = 0; rg < 4; ++rg) rs[mr][rg] = 0.f;
#pragma unroll
    for (int nr = 0; nr < 4; ++nr) cs[nr] = 0.f;

#pragma unroll
    for (int mr = 0; mr < 4; ++mr)
#pragma unroll
        for (int nr = 0; nr < 4; ++nr)
#pragma unroll
            for (int rg = 0; rg < 4; ++rg) {
                float d2 = er[mr][rg] + fc[nr] - 2.f * acc[mr][nr][rg] + deps2;
                float d = sqrtf(fmaxf(d2, 0.f));
                rs[mr][rg] += d;
                cs[nr] += d;
            }

    // row sums: reduce across the 16 lo lanes of each group
#pragma unroll
    for (int mr = 0; mr < 4; ++mr)
#pragma unroll
        for (int rg = 0; rg < 4; ++rg) {
            float v = rs[mr][rg];
            v += __shfl_xor(v, 1);
            v += __shfl_xor(v, 2);
            v += __shfl_xor(v, 4);
            v += __shfl_xor(v, 8);
            if (lo == 0) atomicAdd(&sdrow[wm * 64 + mr * 16 + hi * 4 + rg], v);
        }
    // col sums: reduce across the 4 hi groups
    if (offdiag) {
#pragma unroll
        for (int nr = 0; nr < 4; ++nr) {
            float v = cs[nr];
            v += __shfl_xor(v, 16);
            v += __shfl_xor(v, 32);
            if (hi == 0) atomicAdd(&sdcol[wn * 64 + nr * 16 + lo], v);
        }
    }
    __syncthreads();
    if (t < 128) {
        atomicAdd(&dtot[i0 + t], sdrow[t]);
        if (offdiag) atomicAdd(&dtot[j0 + t], sdcol[t]);
    }
}

__global__ void k_feat(float* ws) {
    int i = blockIdx.x * 256 + threadIdx.x;
    float ratio = 0.f;
    if (i < B) {
        float dp = ws[64 + 2 * B + i];
        float dt = ws[64 + 3 * B + i];
        ratio = dp / (dt - dp);
    }
    for (int o = 32; o; o >>= 1) ratio += __shfl_xor(ratio, o);
    __shared__ float sm[4];
    int w = threadIdx.x >> 6;
    if ((threadIdx.x & 63) == 0) sm[w] = ratio;
    __syncthreads();
    if (threadIdx.x == 0) atomicAdd(ws + 1, sm[0] + sm[1] + sm[2] + sm[3]);
}

__global__ void k_out(const float* __restrict__ ws, float* __restrict__ out) {
    float la = ws[0] / (float)B;
    float lf = ws[1];
    out[0] = la + LAMBD * lf;
    out[1] = la;
    out[2] = lf;
}

extern "C" void kernel_launch(void* const* d_in, const int* in_sizes, int n_in,
                              void* d_out, int out_size, void* d_ws, size_t ws_size,
                              hipStream_t stream) {
    const float* data = (const float*)d_in[0];
    const float* x = (const float*)d_in[1];
    const int* y = (const int*)d_in[2];
    float* out = (float*)d_out;
    float* ws = (float*)d_ws;

    k_init<<<(B + 255) / 256, 256, 0, stream>>>(ws);
    k_rowstats<<<B / 4, 256, 0, stream>>>(x, y, ws);
    k_ce<<<B / 4, 256, 0, stream>>>(data, y, ws);
    k_dpos<<<B / 4, 256, 0, stream>>>(x, y, ws);
    k_gram_dtot<<<dim3(64, 64), 256, 0, stream>>>(x, ws);
    k_feat<<<(B + 255) / 256, 256, 0, stream>>>(ws);
    k_out<<<1, 1, 0, stream>>>(ws, out);
}